// Round 5
// baseline (171.811 us; speedup 1.0000x reference)
//
#include <hip/hip_runtime.h>
#include <stdint.h>

typedef unsigned short u16;
typedef __attribute__((ext_vector_type(8))) __bf16 bf16x8;
typedef __attribute__((ext_vector_type(4))) __bf16 bf16x4;
typedef __attribute__((ext_vector_type(4))) float f32x4;
typedef __attribute__((ext_vector_type(2))) unsigned int u32x2;
typedef __attribute__((ext_vector_type(4))) unsigned int u32x4;

#define QSCALE 0.18033688011112042f /* (1/8) * log2(e) */

__device__ __forceinline__ u16 f2bf(float f) {
    uint32_t u = __builtin_bit_cast(uint32_t, f);
    u = (u + 0x7fffu + ((u >> 16) & 1u)) >> 16;
    return (u16)u;
}
__device__ __forceinline__ float bf2f(u16 h) {
    uint32_t u = ((uint32_t)h) << 16;
    return __builtin_bit_cast(float, u);
}

// async global->LDS, 16B/lane; LDS dest = wave-uniform base + lane*16.
__device__ __forceinline__ void gl_lds16(const u16* g, u16* l) {
    __builtin_amdgcn_global_load_lds(
        (__attribute__((address_space(1))) uint32_t*)(g),
        (__attribute__((address_space(3))) uint32_t*)(l), 16, 0, 0);
}

// ---- x (fp32) -> bf16, 4 elems/thread ----
__global__ __launch_bounds__(256) void convert_x_k(const float* __restrict__ xf,
                                                   u16* __restrict__ xbf) {
    const size_t v = (size_t)blockIdx.x * 256 + threadIdx.x; // float4 index
    const f32x4 val = ((const f32x4*)xf)[v];
    u32x2 p;
    p.x = (uint32_t)f2bf(val.x) | ((uint32_t)f2bf(val.y) << 16);
    p.y = (uint32_t)f2bf(val.z) | ((uint32_t)f2bf(val.w) << 16);
    *(u32x2*)&xbf[v * 4] = p;
}

// ---- weight transpose + cvt: in fp32[R][C] -> out bf16[C][R], 64x64 tiles ----
__global__ void transpose_cvt_k(const float* __restrict__ in,
                                u16* __restrict__ out, int R, int C) {
    __shared__ u16 t[64][65];
    const int bx = blockIdx.x << 6, by = blockIdx.y << 6;
    const int tx = threadIdx.x, ty = threadIdx.y; // 64 x 8
#pragma unroll
    for (int i = ty; i < 64; i += 8)
        t[i][tx] = f2bf(in[(size_t)(by + i) * C + bx + tx]);
    __syncthreads();
#pragma unroll
    for (int i = ty; i < 64; i += 8) out[(size_t)(bx + i) * R + by + tx] = t[tx][i];
}

// ---- m97-style MFMA GEMM, 2-phase pipelined (T3 minimum recipe):
// stage tile k+1 before computing tile k; single barrier per K-step drains.
// C = A(Mx512) * Bt^T + bias. EPI 0: scatter Q(xQSCALE)/K/Vt. EPI 1: fp32 out.
template <int EPI>
__global__ __launch_bounds__(256) void gemm_bt_k(
    const u16* __restrict__ A, const u16* __restrict__ Bt,
    const float* __restrict__ bias,
    u16* __restrict__ Qb, u16* __restrict__ Kb, u16* __restrict__ Vt,
    float* __restrict__ OutF) {
    __shared__ u16 lA[2][128 * 32];
    __shared__ u16 lB[2][128 * 32];
    const int tid = threadIdx.x;
    const int w = tid >> 6, l = tid & 63, quad = l >> 4, r = l & 15;
    const int tm = blockIdx.x << 7, tn = blockIdx.y << 7;
    const int wm = (w >> 1) << 6, wn = (w & 1) << 6;
    const int srow = l >> 2, sch = (l & 3) << 3;

    f32x4 acc[4][4];
#pragma unroll
    for (int i = 0; i < 4; ++i)
#pragma unroll
        for (int j = 0; j < 4; ++j) acc[i][j] = (f32x4){0.f, 0.f, 0.f, 0.f};

    auto stage = [&](int b, int kk) {
#pragma unroll
        for (int ii = 0; ii < 2; ++ii) {
            const int rowl = w * 32 + ii * 16; // wave-uniform
            gl_lds16(A + (size_t)(tm + rowl + srow) * 512 + kk + sch, &lA[b][rowl * 32]);
            gl_lds16(Bt + (size_t)(tn + rowl + srow) * 512 + kk + sch, &lB[b][rowl * 32]);
        }
    };

    stage(0, 0);
    __syncthreads(); // implicit vmcnt(0): tile 0 resident

    int cur = 0;
    for (int kk = 0; kk < 512; kk += 32) {
        if (kk + 32 < 512) stage(cur ^ 1, kk + 32); // in flight during compute
        bf16x8 af[4], bfr[4];
#pragma unroll
        for (int mi = 0; mi < 4; ++mi)
            af[mi] = *(const bf16x8*)&lA[cur][(wm + mi * 16 + r) * 32 + quad * 8];
#pragma unroll
        for (int ni = 0; ni < 4; ++ni)
            bfr[ni] = *(const bf16x8*)&lB[cur][(wn + ni * 16 + r) * 32 + quad * 8];
#pragma unroll
        for (int mi = 0; mi < 4; ++mi)
#pragma unroll
            for (int ni = 0; ni < 4; ++ni)
                acc[mi][ni] = __builtin_amdgcn_mfma_f32_16x16x32_bf16(
                    af[mi], bfr[ni], acc[mi][ni], 0, 0, 0);
        __syncthreads(); // drains next-tile loads (flew during MFMAs) + frag reads
        cur ^= 1;
    }

#pragma unroll
    for (int ni = 0; ni < 4; ++ni) {
        const int n = tn + wn + ni * 16 + r;
        const float bv = bias[n];
        const int which = n >> 9, head = (n >> 6) & 7, d = n & 63;
#pragma unroll
        for (int mi = 0; mi < 4; ++mi) {
#pragma unroll
            for (int i = 0; i < 4; ++i) {
                const int m = tm + wm + mi * 16 + quad * 4 + i;
                const float v = acc[mi][ni][i] + bv;
                if (EPI == 0) {
                    const int bb = m >> 11, t = m & 2047;
                    const int bh = bb * 8 + head;
                    if (which == 0)
                        Qb[((size_t)(bh * 2048 + t) << 6) + d] = f2bf(v * QSCALE);
                    else if (which == 1)
                        Kb[((size_t)(bh * 2048 + t) << 6) + d] = f2bf(v);
                    else
                        Vt[((size_t)(bh * 64 + d) << 11) + t] = f2bf(v);
                } else {
                    OutF[(size_t)m * 512 + n] = v; // fp32 out
                }
            }
        }
    }
}

// ---- MFMA flash attention v7 (resubmit; R4 bench was an infra failure):
// v6's in-register P path (kv-permuted QK, zero bank conflicts) +
// q-fattening: 4 waves x 32 q-rows = 128 q-rows/block. K/V LDS fragments
// read ONCE per wave and reused across both q-subtiles -> LDS bytes per
// unit work halves (the measured bottleneck: ~74% LDS-busy). Grid 16x32 =
// 512 blocks = 2 blocks/CU; per-wave ILP doubles (2 independent q streams)
// to cover the TLP drop. LDS = 32768B. Dbuf K/V, 1 barrier/iter.
__global__ __launch_bounds__(256) void attn_k(
    const u16* __restrict__ Qb, const u16* __restrict__ Kb,
    const u16* __restrict__ Vt, u16* __restrict__ attnb) {
    __shared__ u16 lk[2][64 * 64];
    __shared__ u16 lv[2][64 * 64];
    const int tid = threadIdx.x;
    const int w = tid >> 6, l = tid & 63, quad = l >> 4, r = l & 15;
    const int qt = blockIdx.x, bh = blockIdx.y;
    const size_t qbase = (size_t)bh * 2048 + qt * 128;
    const int srl = l >> 3;
    const int sg = (l & 7) ^ srl; // V staging swizzle (unchanged)

    const int rl = r & 7;
    const int rhi = r >> 3;
    // K-read swizzle for permuted rows: s_k = ri ^ ((rr&1)<<1) ^ ((rr&2)<<1)
    const int skq = (r & 3) ^ (((r >> 2) & 1) << 1) ^ (((r >> 2) & 2) << 1);
    const int g0 = (quad ^ skq) << 3; // stored granule (u16 units)

    // Q fragments: 2 q-subtiles x 2 halves of d
    bf16x8 qf[2][2];
#pragma unroll
    for (int qs = 0; qs < 2; ++qs)
#pragma unroll
        for (int hf = 0; hf < 2; ++hf)
            qf[qs][hf] = *(const bf16x8*)&Qb[((qbase + w * 32 + qs * 16 + r) << 6) +
                                            hf * 32 + quad * 8];

    const u32x4 onesu = {0x3F803F80u, 0x3F803F80u, 0x3F803F80u, 0x3F803F80u};
    const bf16x8 vones = __builtin_bit_cast(bf16x8, onesu); // bf16 1.0 x8

    f32x4 o[2][4];
#pragma unroll
    for (int qs = 0; qs < 2; ++qs)
#pragma unroll
        for (int i = 0; i < 4; ++i) o[qs][i] = (f32x4){0.f, 0.f, 0.f, 0.f};
    f32x4 osum[2];
    osum[0] = (f32x4){0.f, 0.f, 0.f, 0.f};
    osum[1] = (f32x4){0.f, 0.f, 0.f, 0.f};

    auto stage = [&](int b, int kv0) {
#pragma unroll
        for (int ii = 0; ii < 2; ++ii) {
            const int chunk = w * 2 + ii;
            // K: source pre-swizzled so stored granule gs holds true granule
            // gs ^ s_k(row); row = chunk*8 + srl.
            const int skr = (srl & 3) ^ ((chunk & 1) << 1) ^ ((chunk & 2) << 1);
            gl_lds16(Kb + ((size_t)(bh * 2048 + kv0 + chunk * 8 + srl) << 6) +
                         ((l & 7) ^ skr) * 8,
                     &lk[b][chunk * 512]);
            gl_lds16(Vt + (((size_t)(bh * 64 + chunk * 8 + srl)) << 11) + kv0 + sg * 8,
                     &lv[b][chunk * 512]);
        }
    };

    stage(0, 0);
    __syncthreads(); // implicit vmcnt(0): tile 0 resident

    int cur = 0;
    for (int kv0 = 0; kv0 < 2048; kv0 += 64) {
        if (kv0 + 64 < 2048) stage(cur ^ 1, kv0 + 64); // flies under compute

        // QK with permuted K rows: lane (quad,r) ends up holding
        // P[q][kv = (kt&1)*32 + quad*8 + (kt>>1)*4 + i], packed to bf16.
        // K fragments a0/a1 shared across both q-subtiles.
        uint32_t pk[2][4][2];
#pragma unroll
        for (int kt = 0; kt < 4; ++kt) {
            const int R = (kt & 1) * 32 + (r >> 2) * 8 + (kt >> 1) * 4 + (r & 3);
            const bf16x8 a0 = *(const bf16x8*)&lk[cur][R * 64 + g0];
            const bf16x8 a1 = *(const bf16x8*)&lk[cur][(R * 64 + g0) ^ 32];
#pragma unroll
            for (int qs = 0; qs < 2; ++qs) {
                f32x4 z = (f32x4){0.f, 0.f, 0.f, 0.f};
                __builtin_amdgcn_s_setprio(1);
                z = __builtin_amdgcn_mfma_f32_16x16x32_bf16(a0, qf[qs][0], z, 0, 0, 0);
                z = __builtin_amdgcn_mfma_f32_16x16x32_bf16(a1, qf[qs][1], z, 0, 0, 0);
                __builtin_amdgcn_s_setprio(0);
                // p = exp2(s): raw v_exp_f32 (|s|<8), half-up bf16 pack via perm
                const uint32_t u0 =
                    __builtin_bit_cast(uint32_t, __builtin_amdgcn_exp2f(z[0])) + 0x8000u;
                const uint32_t u1 =
                    __builtin_bit_cast(uint32_t, __builtin_amdgcn_exp2f(z[1])) + 0x8000u;
                const uint32_t u2 =
                    __builtin_bit_cast(uint32_t, __builtin_amdgcn_exp2f(z[2])) + 0x8000u;
                const uint32_t u3 =
                    __builtin_bit_cast(uint32_t, __builtin_amdgcn_exp2f(z[3])) + 0x8000u;
                pk[qs][kt][0] = __builtin_amdgcn_perm(u1, u0, 0x07060302u);
                pk[qs][kt][1] = __builtin_amdgcn_perm(u3, u2, 0x07060302u);
            }
        }

        // PV: A-frag[qs][h] = {pk[qs][h], pk[qs][h+2]} in registers;
        // B = V^T tile from LDS, read once and shared across q-subtiles.
        __builtin_amdgcn_s_setprio(1);
#pragma unroll
        for (int h = 0; h < 2; ++h) {
            const u32x4 aw0 = {pk[0][h][0], pk[0][h][1], pk[0][h + 2][0],
                               pk[0][h + 2][1]};
            const u32x4 aw1 = {pk[1][h][0], pk[1][h][1], pk[1][h + 2][0],
                               pk[1][h + 2][1]};
            const bf16x8 ap0 = __builtin_bit_cast(bf16x8, aw0);
            const bf16x8 ap1 = __builtin_bit_cast(bf16x8, aw1);
#pragma unroll
            for (int dt = 0; dt < 4; ++dt) {
                const int baseV = (dt * 2 + rhi) * 512 + rl * 64;
                const bf16x8 bv =
                    *(const bf16x8*)&lv[cur][baseV + ((h * 4 + quad) ^ rl) * 8];
                o[0][dt] =
                    __builtin_amdgcn_mfma_f32_16x16x32_bf16(ap0, bv, o[0][dt], 0, 0, 0);
                o[1][dt] =
                    __builtin_amdgcn_mfma_f32_16x16x32_bf16(ap1, bv, o[1][dt], 0, 0, 0);
            }
            osum[0] = __builtin_amdgcn_mfma_f32_16x16x32_bf16(ap0, vones, osum[0], 0, 0, 0);
            osum[1] = __builtin_amdgcn_mfma_f32_16x16x32_bf16(ap1, vones, osum[1], 0, 0, 0);
        }
        __builtin_amdgcn_s_setprio(0);

        __syncthreads(); // drains next K/V tile loads (flew during QK+exp+PV)
        cur ^= 1;
    }

    const int bb = bh >> 3, head = bh & 7;
#pragma unroll
    for (int qs = 0; qs < 2; ++qs) {
#pragma unroll
        for (int i = 0; i < 4; ++i) {
            const float inv = __builtin_amdgcn_rcpf(osum[qs][i]); // <=1 ulp, fine
            const int row = bb * 2048 + qt * 128 + w * 32 + qs * 16 + quad * 4 + i;
#pragma unroll
            for (int dt = 0; dt < 4; ++dt)
                attnb[(size_t)row * 512 + head * 64 + dt * 16 + r] =
                    f2bf(o[qs][dt][i] * inv);
        }
    }
}

// ---------------- launch ----------------
extern "C" void kernel_launch(void* const* d_in, const int* in_sizes, int n_in,
                              void* d_out, int out_size, void* d_ws, size_t ws_size,
                              hipStream_t stream) {
    const float *x = nullptr, *wq = nullptr, *bq = nullptr, *wp = nullptr, *bp = nullptr;
    for (int i = 0; i < n_in; ++i) {
        switch (in_sizes[i]) {
            case 4194304: x  = (const float*)d_in[i]; break;
            case 786432:  wq = (const float*)d_in[i]; break;
            case 1536:    bq = (const float*)d_in[i]; break;
            case 262144:  wp = (const float*)d_in[i]; break;
            case 512:     bp = (const float*)d_in[i]; break;
        }
    }
    if (!x || !wq || !bq || !wp || !bp) {
        x = (const float*)d_in[0]; wq = (const float*)d_in[1];
        bq = (const float*)d_in[2]; wp = (const float*)d_in[3];
        bp = (const float*)d_in[4];
    }
    float* out = (float*)d_out;

    // ws plan (32 MiB): attnb@0 (wqkvT aliases until attn), Qb@8M (wprojT
    // aliases after attn), Kb@16M, Vt@24M. xbf lives in d_out until proj.
    char* ws = (char*)d_ws;
    u16* attnb  = (u16*)(ws + 0);
    u16* wqkvT  = (u16*)(ws + 0);
    u16* Qb     = (u16*)(ws + 8388608);
    u16* wprojT = (u16*)(ws + 8388608);
    u16* Kb     = (u16*)(ws + 16777216);
    u16* Vt     = (u16*)(ws + 25165824);
    u16* xbf    = (u16*)d_out;

    convert_x_k<<<dim3(4096), 256, 0, stream>>>(x, xbf);
    transpose_cvt_k<<<dim3(24, 8), dim3(64, 8), 0, stream>>>(wq, wqkvT, 512, 1536);
    gemm_bt_k<0><<<dim3(64, 12), 256, 0, stream>>>(xbf, wqkvT, bq, Qb, Kb, Vt, nullptr);
    attn_k<<<dim3(16, 32), 256, 0, stream>>>(Qb, Kb, Vt, attnb);
    transpose_cvt_k<<<dim3(8, 8), dim3(64, 8), 0, stream>>>(wp, wprojT, 512, 512);
    gemm_bt_k<1><<<dim3(64, 4), 256, 0, stream>>>(attnb, wprojT, bp, nullptr, nullptr,
                                                  nullptr, out);
}

// Round 6
// 163.821 us; speedup vs baseline: 1.0488x; 1.0488x over previous
//
#include <hip/hip_runtime.h>
#include <stdint.h>

typedef unsigned short u16;
typedef __attribute__((ext_vector_type(8))) __bf16 bf16x8;
typedef __attribute__((ext_vector_type(4))) __bf16 bf16x4;
typedef __attribute__((ext_vector_type(4))) float f32x4;
typedef __attribute__((ext_vector_type(2))) unsigned int u32x2;
typedef __attribute__((ext_vector_type(4))) unsigned int u32x4;

#define QSCALE 0.18033688011112042f /* (1/8) * log2(e) */

__device__ __forceinline__ u16 f2bf(float f) {
    uint32_t u = __builtin_bit_cast(uint32_t, f);
    u = (u + 0x7fffu + ((u >> 16) & 1u)) >> 16;
    return (u16)u;
}
__device__ __forceinline__ float bf2f(u16 h) {
    uint32_t u = ((uint32_t)h) << 16;
    return __builtin_bit_cast(float, u);
}

// async global->LDS, 16B/lane; LDS dest = wave-uniform base + lane*16.
__device__ __forceinline__ void gl_lds16(const u16* g, u16* l) {
    __builtin_amdgcn_global_load_lds(
        (__attribute__((address_space(1))) uint32_t*)(g),
        (__attribute__((address_space(3))) uint32_t*)(l), 16, 0, 0);
}

// ---- x (fp32) -> bf16, 4 elems/thread ----
__global__ __launch_bounds__(256) void convert_x_k(const float* __restrict__ xf,
                                                   u16* __restrict__ xbf) {
    const size_t v = (size_t)blockIdx.x * 256 + threadIdx.x; // float4 index
    const f32x4 val = ((const f32x4*)xf)[v];
    u32x2 p;
    p.x = (uint32_t)f2bf(val.x) | ((uint32_t)f2bf(val.y) << 16);
    p.y = (uint32_t)f2bf(val.z) | ((uint32_t)f2bf(val.w) << 16);
    *(u32x2*)&xbf[v * 4] = p;
}

// ---- weight transpose + cvt: in fp32[R][C] -> out bf16[C][R], 64x64 tiles ----
__global__ void transpose_cvt_k(const float* __restrict__ in,
                                u16* __restrict__ out, int R, int C) {
    __shared__ u16 t[64][65];
    const int bx = blockIdx.x << 6, by = blockIdx.y << 6;
    const int tx = threadIdx.x, ty = threadIdx.y; // 64 x 8
#pragma unroll
    for (int i = ty; i < 64; i += 8)
        t[i][tx] = f2bf(in[(size_t)(by + i) * C + bx + tx]);
    __syncthreads();
#pragma unroll
    for (int i = ty; i < 64; i += 8) out[(size_t)(bx + i) * R + by + tx] = t[tx][i];
}

// ---- m97-style MFMA GEMM, 2-phase pipelined (T3 minimum recipe):
// stage tile k+1 before computing tile k; single barrier per K-step drains.
// C = A(Mx512) * Bt^T + bias. EPI 0: scatter Q(xQSCALE)/K/Vt. EPI 1: fp32 out.
template <int EPI>
__global__ __launch_bounds__(256) void gemm_bt_k(
    const u16* __restrict__ A, const u16* __restrict__ Bt,
    const float* __restrict__ bias,
    u16* __restrict__ Qb, u16* __restrict__ Kb, u16* __restrict__ Vt,
    float* __restrict__ OutF) {
    __shared__ u16 lA[2][128 * 32];
    __shared__ u16 lB[2][128 * 32];
    const int tid = threadIdx.x;
    const int w = tid >> 6, l = tid & 63, quad = l >> 4, r = l & 15;
    const int tm = blockIdx.x << 7, tn = blockIdx.y << 7;
    const int wm = (w >> 1) << 6, wn = (w & 1) << 6;
    const int srow = l >> 2, sch = (l & 3) << 3;

    f32x4 acc[4][4];
#pragma unroll
    for (int i = 0; i < 4; ++i)
#pragma unroll
        for (int j = 0; j < 4; ++j) acc[i][j] = (f32x4){0.f, 0.f, 0.f, 0.f};

    auto stage = [&](int b, int kk) {
#pragma unroll
        for (int ii = 0; ii < 2; ++ii) {
            const int rowl = w * 32 + ii * 16; // wave-uniform
            gl_lds16(A + (size_t)(tm + rowl + srow) * 512 + kk + sch, &lA[b][rowl * 32]);
            gl_lds16(Bt + (size_t)(tn + rowl + srow) * 512 + kk + sch, &lB[b][rowl * 32]);
        }
    };

    stage(0, 0);
    __syncthreads(); // implicit vmcnt(0): tile 0 resident

    int cur = 0;
    for (int kk = 0; kk < 512; kk += 32) {
        if (kk + 32 < 512) stage(cur ^ 1, kk + 32); // in flight during compute
        bf16x8 af[4], bfr[4];
#pragma unroll
        for (int mi = 0; mi < 4; ++mi)
            af[mi] = *(const bf16x8*)&lA[cur][(wm + mi * 16 + r) * 32 + quad * 8];
#pragma unroll
        for (int ni = 0; ni < 4; ++ni)
            bfr[ni] = *(const bf16x8*)&lB[cur][(wn + ni * 16 + r) * 32 + quad * 8];
#pragma unroll
        for (int mi = 0; mi < 4; ++mi)
#pragma unroll
            for (int ni = 0; ni < 4; ++ni)
                acc[mi][ni] = __builtin_amdgcn_mfma_f32_16x16x32_bf16(
                    af[mi], bfr[ni], acc[mi][ni], 0, 0, 0);
        __syncthreads(); // drains next-tile loads (flew during MFMAs) + frag reads
        cur ^= 1;
    }

#pragma unroll
    for (int ni = 0; ni < 4; ++ni) {
        const int n = tn + wn + ni * 16 + r;
        const float bv = bias[n];
        const int which = n >> 9, head = (n >> 6) & 7, d = n & 63;
#pragma unroll
        for (int mi = 0; mi < 4; ++mi) {
#pragma unroll
            for (int i = 0; i < 4; ++i) {
                const int m = tm + wm + mi * 16 + quad * 4 + i;
                const float v = acc[mi][ni][i] + bv;
                if (EPI == 0) {
                    const int bb = m >> 11, t = m & 2047;
                    const int bh = bb * 8 + head;
                    if (which == 0)
                        Qb[((size_t)(bh * 2048 + t) << 6) + d] = f2bf(v * QSCALE);
                    else if (which == 1)
                        Kb[((size_t)(bh * 2048 + t) << 6) + d] = f2bf(v);
                    else
                        Vt[((size_t)(bh * 64 + d) << 11) + t] = f2bf(v);
                } else {
                    OutF[(size_t)m * 512 + n] = v; // fp32 out
                }
            }
        }
    }
}

// ---- MFMA flash attention v8: v7 shape (4 waves x 32 q-rows, 2 blocks/CU,
// in-register P path, zero bank conflicts) + scheduling freedom:
// __launch_bounds__(256,2) raises the VGPR budget to match the ACTUAL
// occupancy (2 waves/EU) -- v7's 64-VGPR squeeze serialized ds_read->use
// chains (~4.1k cy/iter critical path, all pipes <50% busy). All 16
// ds_read_b128 (8 K-frags + 8 V-frags) hoisted to iteration start; bf16
// pack via plain casts (compiler emits v_cvt_pk_bf16_f32; drops add+perm).
__global__ __launch_bounds__(256, 2) void attn_k(
    const u16* __restrict__ Qb, const u16* __restrict__ Kb,
    const u16* __restrict__ Vt, u16* __restrict__ attnb) {
    __shared__ u16 lk[2][64 * 64];
    __shared__ u16 lv[2][64 * 64];
    const int tid = threadIdx.x;
    const int w = tid >> 6, l = tid & 63, quad = l >> 4, r = l & 15;
    const int qt = blockIdx.x, bh = blockIdx.y;
    const size_t qbase = (size_t)bh * 2048 + qt * 128;
    const int srl = l >> 3;
    const int sg = (l & 7) ^ srl; // V staging swizzle (unchanged)

    const int rl = r & 7;
    const int rhi = r >> 3;
    // K-read swizzle for permuted rows: s_k = ri ^ ((rr&1)<<1) ^ ((rr&2)<<1)
    const int skq = (r & 3) ^ (((r >> 2) & 1) << 1) ^ (((r >> 2) & 2) << 1);
    const int g0 = (quad ^ skq) << 3; // stored granule (u16 units)

    // Q fragments: 2 q-subtiles x 2 halves of d
    bf16x8 qf[2][2];
#pragma unroll
    for (int qs = 0; qs < 2; ++qs)
#pragma unroll
        for (int hf = 0; hf < 2; ++hf)
            qf[qs][hf] = *(const bf16x8*)&Qb[((qbase + w * 32 + qs * 16 + r) << 6) +
                                            hf * 32 + quad * 8];

    const u32x4 onesu = {0x3F803F80u, 0x3F803F80u, 0x3F803F80u, 0x3F803F80u};
    const bf16x8 vones = __builtin_bit_cast(bf16x8, onesu); // bf16 1.0 x8

    f32x4 o[2][4];
#pragma unroll
    for (int qs = 0; qs < 2; ++qs)
#pragma unroll
        for (int i = 0; i < 4; ++i) o[qs][i] = (f32x4){0.f, 0.f, 0.f, 0.f};
    f32x4 osum[2];
    osum[0] = (f32x4){0.f, 0.f, 0.f, 0.f};
    osum[1] = (f32x4){0.f, 0.f, 0.f, 0.f};

    auto stage = [&](int b, int kv0) {
#pragma unroll
        for (int ii = 0; ii < 2; ++ii) {
            const int chunk = w * 2 + ii;
            // K: source pre-swizzled so stored granule gs holds true granule
            // gs ^ s_k(row); row = chunk*8 + srl.
            const int skr = (srl & 3) ^ ((chunk & 1) << 1) ^ ((chunk & 2) << 1);
            gl_lds16(Kb + ((size_t)(bh * 2048 + kv0 + chunk * 8 + srl) << 6) +
                         ((l & 7) ^ skr) * 8,
                     &lk[b][chunk * 512]);
            gl_lds16(Vt + (((size_t)(bh * 64 + chunk * 8 + srl)) << 11) + kv0 + sg * 8,
                     &lv[b][chunk * 512]);
        }
    };

    stage(0, 0);
    __syncthreads(); // implicit vmcnt(0): tile 0 resident

    int cur = 0;
    for (int kv0 = 0; kv0 < 2048; kv0 += 64) {
        if (kv0 + 64 < 2048) stage(cur ^ 1, kv0 + 64); // flies under compute

        // ---- hoisted LDS reads: all 16 ds_read_b128 issued up front ----
        bf16x8 ka[4], kb[4]; // K fragments (shared across q-subtiles)
#pragma unroll
        for (int kt = 0; kt < 4; ++kt) {
            const int R = (kt & 1) * 32 + (r >> 2) * 8 + (kt >> 1) * 4 + (r & 3);
            ka[kt] = *(const bf16x8*)&lk[cur][R * 64 + g0];
            kb[kt] = *(const bf16x8*)&lk[cur][(R * 64 + g0) ^ 32];
        }
        bf16x8 vb[2][4]; // V^T fragments (shared across q-subtiles)
#pragma unroll
        for (int h = 0; h < 2; ++h)
#pragma unroll
            for (int dt = 0; dt < 4; ++dt) {
                const int baseV = (dt * 2 + rhi) * 512 + rl * 64;
                vb[h][dt] = *(const bf16x8*)&lv[cur][baseV + ((h * 4 + quad) ^ rl) * 8];
            }

        // QK with permuted K rows: lane (quad,r) ends up holding
        // P[q][kv = (kt&1)*32 + quad*8 + (kt>>1)*4 + i]; bf16 via cvt_pk.
        bf16x4 pk4[2][4];
#pragma unroll
        for (int kt = 0; kt < 4; ++kt) {
#pragma unroll
            for (int qs = 0; qs < 2; ++qs) {
                f32x4 z = (f32x4){0.f, 0.f, 0.f, 0.f};
                __builtin_amdgcn_s_setprio(1);
                z = __builtin_amdgcn_mfma_f32_16x16x32_bf16(ka[kt], qf[qs][0], z, 0, 0, 0);
                z = __builtin_amdgcn_mfma_f32_16x16x32_bf16(kb[kt], qf[qs][1], z, 0, 0, 0);
                __builtin_amdgcn_s_setprio(0);
                // p = exp2(s): raw v_exp_f32 (|s|<8); plain casts -> compiler
                // emits v_cvt_pk_bf16_f32 pairs (RNE)
                bf16x4 pb;
                pb[0] = (__bf16)__builtin_amdgcn_exp2f(z[0]);
                pb[1] = (__bf16)__builtin_amdgcn_exp2f(z[1]);
                pb[2] = (__bf16)__builtin_amdgcn_exp2f(z[2]);
                pb[3] = (__bf16)__builtin_amdgcn_exp2f(z[3]);
                pk4[qs][kt] = pb;
            }
        }

        // PV: A-frag[qs][h] = {pk4[qs][h], pk4[qs][h+2]} in registers;
        // B = hoisted V^T fragments; + ones-MFMA row sums
        __builtin_amdgcn_s_setprio(1);
#pragma unroll
        for (int h = 0; h < 2; ++h) {
            const bf16x8 ap0 = __builtin_shufflevector(pk4[0][h], pk4[0][h + 2],
                                                       0, 1, 2, 3, 4, 5, 6, 7);
            const bf16x8 ap1 = __builtin_shufflevector(pk4[1][h], pk4[1][h + 2],
                                                       0, 1, 2, 3, 4, 5, 6, 7);
#pragma unroll
            for (int dt = 0; dt < 4; ++dt) {
                o[0][dt] = __builtin_amdgcn_mfma_f32_16x16x32_bf16(ap0, vb[h][dt],
                                                                  o[0][dt], 0, 0, 0);
                o[1][dt] = __builtin_amdgcn_mfma_f32_16x16x32_bf16(ap1, vb[h][dt],
                                                                  o[1][dt], 0, 0, 0);
            }
            osum[0] = __builtin_amdgcn_mfma_f32_16x16x32_bf16(ap0, vones, osum[0], 0, 0, 0);
            osum[1] = __builtin_amdgcn_mfma_f32_16x16x32_bf16(ap1, vones, osum[1], 0, 0, 0);
        }
        __builtin_amdgcn_s_setprio(0);

        __syncthreads(); // drains next K/V tile loads (flew during QK+exp+PV)
        cur ^= 1;
    }

    const int bb = bh >> 3, head = bh & 7;
#pragma unroll
    for (int qs = 0; qs < 2; ++qs) {
#pragma unroll
        for (int i = 0; i < 4; ++i) {
            const float inv = __builtin_amdgcn_rcpf(osum[qs][i]); // <=1 ulp, fine
            const int row = bb * 2048 + qt * 128 + w * 32 + qs * 16 + quad * 4 + i;
#pragma unroll
            for (int dt = 0; dt < 4; ++dt)
                attnb[(size_t)row * 512 + head * 64 + dt * 16 + r] =
                    f2bf(o[qs][dt][i] * inv);
        }
    }
}

// ---------------- launch ----------------
extern "C" void kernel_launch(void* const* d_in, const int* in_sizes, int n_in,
                              void* d_out, int out_size, void* d_ws, size_t ws_size,
                              hipStream_t stream) {
    const float *x = nullptr, *wq = nullptr, *bq = nullptr, *wp = nullptr, *bp = nullptr;
    for (int i = 0; i < n_in; ++i) {
        switch (in_sizes[i]) {
            case 4194304: x  = (const float*)d_in[i]; break;
            case 786432:  wq = (const float*)d_in[i]; break;
            case 1536:    bq = (const float*)d_in[i]; break;
            case 262144:  wp = (const float*)d_in[i]; break;
            case 512:     bp = (const float*)d_in[i]; break;
        }
    }
    if (!x || !wq || !bq || !wp || !bp) {
        x = (const float*)d_in[0]; wq = (const float*)d_in[1];
        bq = (const float*)d_in[2]; wp = (const float*)d_in[3];
        bp = (const float*)d_in[4];
    }
    float* out = (float*)d_out;

    // ws plan (32 MiB): attnb@0 (wqkvT aliases until attn), Qb@8M (wprojT
    // aliases after attn), Kb@16M, Vt@24M. xbf lives in d_out until proj.
    char* ws = (char*)d_ws;
    u16* attnb  = (u16*)(ws + 0);
    u16* wqkvT  = (u16*)(ws + 0);
    u16* Qb     = (u16*)(ws + 8388608);
    u16* wprojT = (u16*)(ws + 8388608);
    u16* Kb     = (u16*)(ws + 16777216);
    u16* Vt     = (u16*)(ws + 25165824);
    u16* xbf    = (u16*)d_out;

    convert_x_k<<<dim3(4096), 256, 0, stream>>>(x, xbf);
    transpose_cvt_k<<<dim3(24, 8), dim3(64, 8), 0, stream>>>(wq, wqkvT, 512, 1536);
    gemm_bt_k<0><<<dim3(64, 12), 256, 0, stream>>>(xbf, wqkvT, bq, Qb, Kb, Vt, nullptr);
    attn_k<<<dim3(16, 32), 256, 0, stream>>>(Qb, Kb, Vt, attnb);
    transpose_cvt_k<<<dim3(8, 8), dim3(64, 8), 0, stream>>>(wp, wprojT, 512, 512);
    gemm_bt_k<1><<<dim3(64, 4), 256, 0, stream>>>(attnb, wprojT, bp, nullptr, nullptr,
                                                  nullptr, out);
}

// Round 7
// 162.817 us; speedup vs baseline: 1.0552x; 1.0062x over previous
//
#include <hip/hip_runtime.h>
#include <stdint.h>

typedef unsigned short u16;
typedef __attribute__((ext_vector_type(8))) __bf16 bf16x8;
typedef __attribute__((ext_vector_type(4))) __bf16 bf16x4;
typedef __attribute__((ext_vector_type(4))) float f32x4;
typedef __attribute__((ext_vector_type(2))) unsigned int u32x2;
typedef __attribute__((ext_vector_type(4))) unsigned int u32x4;

#define QSCALE 0.18033688011112042f /* (1/8) * log2(e) */

__device__ __forceinline__ u16 f2bf(float f) {
    uint32_t u = __builtin_bit_cast(uint32_t, f);
    u = (u + 0x7fffu + ((u >> 16) & 1u)) >> 16;
    return (u16)u;
}
__device__ __forceinline__ float bf2f(u16 h) {
    uint32_t u = ((uint32_t)h) << 16;
    return __builtin_bit_cast(float, u);
}

// async global->LDS, 16B/lane; LDS dest = wave-uniform base + lane*16.
__device__ __forceinline__ void gl_lds16(const u16* g, u16* l) {
    __builtin_amdgcn_global_load_lds(
        (__attribute__((address_space(1))) uint32_t*)(g),
        (__attribute__((address_space(3))) uint32_t*)(l), 16, 0, 0);
}

// ---- fused prep: x fp32->bf16 (blocks 0..4095) + wqkv transpose-cvt
// (blocks 4096..4287). wp transpose CANNOT fuse here: wprojT aliases Qb,
// which gemm0 writes -- it stays after attn.
__global__ __launch_bounds__(256) void prep_k(const float* __restrict__ xf,
                                              u16* __restrict__ xbf,
                                              const float* __restrict__ wq,
                                              u16* __restrict__ wqkvT) {
    __shared__ u16 t[64][65];
    const int b = blockIdx.x;
    const int tid = threadIdx.x;
    if (b < 4096) {
        const size_t v = (size_t)b * 256 + tid; // float4 index
        const f32x4 val = ((const f32x4*)xf)[v];
        u32x2 p;
        p.x = (uint32_t)f2bf(val.x) | ((uint32_t)f2bf(val.y) << 16);
        p.y = (uint32_t)f2bf(val.z) | ((uint32_t)f2bf(val.w) << 16);
        *(u32x2*)&xbf[v * 4] = p;
    } else {
        const int bb = b - 4096; // 24 x 8 tiles over [512][1536]
        const int bx = (bb % 24) << 6, by = (bb / 24) << 6;
        const int tx = tid & 63, ty = tid >> 6; // 64 x 4
#pragma unroll
        for (int i = ty; i < 64; i += 4)
            t[i][tx] = f2bf(wq[(size_t)(by + i) * 1536 + bx + tx]);
        __syncthreads();
#pragma unroll
        for (int i = ty; i < 64; i += 4)
            wqkvT[(size_t)(bx + i) * 512 + by + tx] = t[tx][i];
    }
}

// ---- weight transpose + cvt: in fp32[R][C] -> out bf16[C][R], 64x64 tiles ----
__global__ void transpose_cvt_k(const float* __restrict__ in,
                                u16* __restrict__ out, int R, int C) {
    __shared__ u16 t[64][65];
    const int bx = blockIdx.x << 6, by = blockIdx.y << 6;
    const int tx = threadIdx.x, ty = threadIdx.y; // 64 x 8
#pragma unroll
    for (int i = ty; i < 64; i += 8)
        t[i][tx] = f2bf(in[(size_t)(by + i) * C + bx + tx]);
    __syncthreads();
#pragma unroll
    for (int i = ty; i < 64; i += 8) out[(size_t)(bx + i) * R + by + tx] = t[tx][i];
}

// ---- m97-style MFMA GEMM, 2-phase pipelined. C = A(Mx512) * Bt^T + bias.
// Tile 128 x BN. BN=128: 4 waves as 2x2 (64x64 each). BN=64: 4 waves
// stacked in M (32 rows each) -> grid 2x denser (gemm1 was 1 block/CU).
// __launch_bounds__(256,3): R6 showed hipcc's default squeezes VGPR for
// phantom occupancy; cap at 3 waves/EU (= the 3 blocks/CU the grid gives).
// EPI 0: scatter Q(xQSCALE)/K/Vt. EPI 1: fp32 out.
template <int EPI, int BN>
__global__ __launch_bounds__(256, 3) void gemm_bt_k(
    const u16* __restrict__ A, const u16* __restrict__ Bt,
    const float* __restrict__ bias,
    u16* __restrict__ Qb, u16* __restrict__ Kb, u16* __restrict__ Vt,
    float* __restrict__ OutF) {
    constexpr int MI = (BN == 128) ? 4 : 2;
    __shared__ u16 lA[2][128 * 32];
    __shared__ u16 lB[2][BN * 32];
    const int tid = threadIdx.x;
    const int w = tid >> 6, l = tid & 63, quad = l >> 4, r = l & 15;
    const int tm = blockIdx.x << 7;
    const int tn = blockIdx.y * BN;
    const int wm = (BN == 128) ? ((w >> 1) << 6) : (w << 5);
    const int wn = (BN == 128) ? ((w & 1) << 6) : 0;
    const int srow = l >> 2, sch = (l & 3) << 3;

    f32x4 acc[MI][4];
#pragma unroll
    for (int i = 0; i < MI; ++i)
#pragma unroll
        for (int j = 0; j < 4; ++j) acc[i][j] = (f32x4){0.f, 0.f, 0.f, 0.f};

    auto stage = [&](int b, int kk) {
#pragma unroll
        for (int ii = 0; ii < 2; ++ii) {
            const int rowl = w * 32 + ii * 16; // wave-uniform
            gl_lds16(A + (size_t)(tm + rowl + srow) * 512 + kk + sch, &lA[b][rowl * 32]);
        }
        if (BN == 128) {
#pragma unroll
            for (int ii = 0; ii < 2; ++ii) {
                const int rowl = w * 32 + ii * 16;
                gl_lds16(Bt + (size_t)(tn + rowl + srow) * 512 + kk + sch,
                         &lB[b][rowl * 32]);
            }
        } else {
            const int rowl = w * 16;
            gl_lds16(Bt + (size_t)(tn + rowl + srow) * 512 + kk + sch,
                     &lB[b][rowl * 32]);
        }
    };

    stage(0, 0);
    __syncthreads(); // implicit vmcnt(0): tile 0 resident

    int cur = 0;
    for (int kk = 0; kk < 512; kk += 32) {
        if (kk + 32 < 512) stage(cur ^ 1, kk + 32); // in flight during compute
        bf16x8 af[MI], bfr[4];
#pragma unroll
        for (int mi = 0; mi < MI; ++mi)
            af[mi] = *(const bf16x8*)&lA[cur][(wm + mi * 16 + r) * 32 + quad * 8];
#pragma unroll
        for (int ni = 0; ni < 4; ++ni)
            bfr[ni] = *(const bf16x8*)&lB[cur][(wn + ni * 16 + r) * 32 + quad * 8];
#pragma unroll
        for (int mi = 0; mi < MI; ++mi)
#pragma unroll
            for (int ni = 0; ni < 4; ++ni)
                acc[mi][ni] = __builtin_amdgcn_mfma_f32_16x16x32_bf16(
                    af[mi], bfr[ni], acc[mi][ni], 0, 0, 0);
        __syncthreads(); // drains next-tile loads (flew during MFMAs) + frag reads
        cur ^= 1;
    }

#pragma unroll
    for (int ni = 0; ni < 4; ++ni) {
        const int n = tn + wn + ni * 16 + r;
        const float bv = bias[n];
        const int which = n >> 9, head = (n >> 6) & 7, d = n & 63;
#pragma unroll
        for (int mi = 0; mi < MI; ++mi) {
#pragma unroll
            for (int i = 0; i < 4; ++i) {
                const int m = tm + wm + mi * 16 + quad * 4 + i;
                const float v = acc[mi][ni][i] + bv;
                if (EPI == 0) {
                    const int bb = m >> 11, t = m & 2047;
                    const int bh = bb * 8 + head;
                    if (which == 0)
                        Qb[((size_t)(bh * 2048 + t) << 6) + d] = f2bf(v * QSCALE);
                    else if (which == 1)
                        Kb[((size_t)(bh * 2048 + t) << 6) + d] = f2bf(v);
                    else
                        Vt[((size_t)(bh * 64 + d) << 11) + t] = f2bf(v);
                } else {
                    OutF[(size_t)m * 512 + n] = v; // fp32 out
                }
            }
        }
    }
}

// ---- MFMA flash attention v8 (frozen from R6): 4 waves x 32 q-rows,
// in-register P path via kv-permuted QK, zero bank conflicts, hoisted
// ds_reads, launch_bounds(256,2), cvt_pk bf16 pack.
__global__ __launch_bounds__(256, 2) void attn_k(
    const u16* __restrict__ Qb, const u16* __restrict__ Kb,
    const u16* __restrict__ Vt, u16* __restrict__ attnb) {
    __shared__ u16 lk[2][64 * 64];
    __shared__ u16 lv[2][64 * 64];
    const int tid = threadIdx.x;
    const int w = tid >> 6, l = tid & 63, quad = l >> 4, r = l & 15;
    const int qt = blockIdx.x, bh = blockIdx.y;
    const size_t qbase = (size_t)bh * 2048 + qt * 128;
    const int srl = l >> 3;
    const int sg = (l & 7) ^ srl; // V staging swizzle (unchanged)

    const int rl = r & 7;
    const int rhi = r >> 3;
    // K-read swizzle for permuted rows: s_k = ri ^ ((rr&1)<<1) ^ ((rr&2)<<1)
    const int skq = (r & 3) ^ (((r >> 2) & 1) << 1) ^ (((r >> 2) & 2) << 1);
    const int g0 = (quad ^ skq) << 3; // stored granule (u16 units)

    // Q fragments: 2 q-subtiles x 2 halves of d
    bf16x8 qf[2][2];
#pragma unroll
    for (int qs = 0; qs < 2; ++qs)
#pragma unroll
        for (int hf = 0; hf < 2; ++hf)
            qf[qs][hf] = *(const bf16x8*)&Qb[((qbase + w * 32 + qs * 16 + r) << 6) +
                                            hf * 32 + quad * 8];

    const u32x4 onesu = {0x3F803F80u, 0x3F803F80u, 0x3F803F80u, 0x3F803F80u};
    const bf16x8 vones = __builtin_bit_cast(bf16x8, onesu); // bf16 1.0 x8

    f32x4 o[2][4];
#pragma unroll
    for (int qs = 0; qs < 2; ++qs)
#pragma unroll
        for (int i = 0; i < 4; ++i) o[qs][i] = (f32x4){0.f, 0.f, 0.f, 0.f};
    f32x4 osum[2];
    osum[0] = (f32x4){0.f, 0.f, 0.f, 0.f};
    osum[1] = (f32x4){0.f, 0.f, 0.f, 0.f};

    auto stage = [&](int b, int kv0) {
#pragma unroll
        for (int ii = 0; ii < 2; ++ii) {
            const int chunk = w * 2 + ii;
            // K: source pre-swizzled so stored granule gs holds true granule
            // gs ^ s_k(row); row = chunk*8 + srl.
            const int skr = (srl & 3) ^ ((chunk & 1) << 1) ^ ((chunk & 2) << 1);
            gl_lds16(Kb + ((size_t)(bh * 2048 + kv0 + chunk * 8 + srl) << 6) +
                         ((l & 7) ^ skr) * 8,
                     &lk[b][chunk * 512]);
            gl_lds16(Vt + (((size_t)(bh * 64 + chunk * 8 + srl)) << 11) + kv0 + sg * 8,
                     &lv[b][chunk * 512]);
        }
    };

    stage(0, 0);
    __syncthreads(); // implicit vmcnt(0): tile 0 resident

    int cur = 0;
    for (int kv0 = 0; kv0 < 2048; kv0 += 64) {
        if (kv0 + 64 < 2048) stage(cur ^ 1, kv0 + 64); // flies under compute

        // ---- hoisted LDS reads: all 16 ds_read_b128 issued up front ----
        bf16x8 ka[4], kb[4]; // K fragments (shared across q-subtiles)
#pragma unroll
        for (int kt = 0; kt < 4; ++kt) {
            const int R = (kt & 1) * 32 + (r >> 2) * 8 + (kt >> 1) * 4 + (r & 3);
            ka[kt] = *(const bf16x8*)&lk[cur][R * 64 + g0];
            kb[kt] = *(const bf16x8*)&lk[cur][(R * 64 + g0) ^ 32];
        }
        bf16x8 vb[2][4]; // V^T fragments (shared across q-subtiles)
#pragma unroll
        for (int h = 0; h < 2; ++h)
#pragma unroll
            for (int dt = 0; dt < 4; ++dt) {
                const int baseV = (dt * 2 + rhi) * 512 + rl * 64;
                vb[h][dt] = *(const bf16x8*)&lv[cur][baseV + ((h * 4 + quad) ^ rl) * 8];
            }

        // QK with permuted K rows: lane (quad,r) ends up holding
        // P[q][kv = (kt&1)*32 + quad*8 + (kt>>1)*4 + i]; bf16 via cvt_pk.
        bf16x4 pk4[2][4];
#pragma unroll
        for (int kt = 0; kt < 4; ++kt) {
#pragma unroll
            for (int qs = 0; qs < 2; ++qs) {
                f32x4 z = (f32x4){0.f, 0.f, 0.f, 0.f};
                __builtin_amdgcn_s_setprio(1);
                z = __builtin_amdgcn_mfma_f32_16x16x32_bf16(ka[kt], qf[qs][0], z, 0, 0, 0);
                z = __builtin_amdgcn_mfma_f32_16x16x32_bf16(kb[kt], qf[qs][1], z, 0, 0, 0);
                __builtin_amdgcn_s_setprio(0);
                // p = exp2(s): raw v_exp_f32 (|s|<8); plain casts -> compiler
                // emits v_cvt_pk_bf16_f32 pairs (RNE)
                bf16x4 pb;
                pb[0] = (__bf16)__builtin_amdgcn_exp2f(z[0]);
                pb[1] = (__bf16)__builtin_amdgcn_exp2f(z[1]);
                pb[2] = (__bf16)__builtin_amdgcn_exp2f(z[2]);
                pb[3] = (__bf16)__builtin_amdgcn_exp2f(z[3]);
                pk4[qs][kt] = pb;
            }
        }

        // PV: A-frag[qs][h] = {pk4[qs][h], pk4[qs][h+2]} in registers;
        // B = hoisted V^T fragments; + ones-MFMA row sums
        __builtin_amdgcn_s_setprio(1);
#pragma unroll
        for (int h = 0; h < 2; ++h) {
            const bf16x8 ap0 = __builtin_shufflevector(pk4[0][h], pk4[0][h + 2],
                                                       0, 1, 2, 3, 4, 5, 6, 7);
            const bf16x8 ap1 = __builtin_shufflevector(pk4[1][h], pk4[1][h + 2],
                                                       0, 1, 2, 3, 4, 5, 6, 7);
#pragma unroll
            for (int dt = 0; dt < 4; ++dt) {
                o[0][dt] = __builtin_amdgcn_mfma_f32_16x16x32_bf16(ap0, vb[h][dt],
                                                                  o[0][dt], 0, 0, 0);
                o[1][dt] = __builtin_amdgcn_mfma_f32_16x16x32_bf16(ap1, vb[h][dt],
                                                                  o[1][dt], 0, 0, 0);
            }
            osum[0] = __builtin_amdgcn_mfma_f32_16x16x32_bf16(ap0, vones, osum[0], 0, 0, 0);
            osum[1] = __builtin_amdgcn_mfma_f32_16x16x32_bf16(ap1, vones, osum[1], 0, 0, 0);
        }
        __builtin_amdgcn_s_setprio(0);

        __syncthreads(); // drains next K/V tile loads (flew during QK+exp+PV)
        cur ^= 1;
    }

    const int bb = bh >> 3, head = bh & 7;
#pragma unroll
    for (int qs = 0; qs < 2; ++qs) {
#pragma unroll
        for (int i = 0; i < 4; ++i) {
            const float inv = __builtin_amdgcn_rcpf(osum[qs][i]); // <=1 ulp, fine
            const int row = bb * 2048 + qt * 128 + w * 32 + qs * 16 + quad * 4 + i;
#pragma unroll
            for (int dt = 0; dt < 4; ++dt)
                attnb[(size_t)row * 512 + head * 64 + dt * 16 + r] =
                    f2bf(o[qs][dt][i] * inv);
        }
    }
}

// ---------------- launch ----------------
extern "C" void kernel_launch(void* const* d_in, const int* in_sizes, int n_in,
                              void* d_out, int out_size, void* d_ws, size_t ws_size,
                              hipStream_t stream) {
    const float *x = nullptr, *wq = nullptr, *bq = nullptr, *wp = nullptr, *bp = nullptr;
    for (int i = 0; i < n_in; ++i) {
        switch (in_sizes[i]) {
            case 4194304: x  = (const float*)d_in[i]; break;
            case 786432:  wq = (const float*)d_in[i]; break;
            case 1536:    bq = (const float*)d_in[i]; break;
            case 262144:  wp = (const float*)d_in[i]; break;
            case 512:     bp = (const float*)d_in[i]; break;
        }
    }
    if (!x || !wq || !bq || !wp || !bp) {
        x = (const float*)d_in[0]; wq = (const float*)d_in[1];
        bq = (const float*)d_in[2]; wp = (const float*)d_in[3];
        bp = (const float*)d_in[4];
    }
    float* out = (float*)d_out;

    // ws plan (32 MiB): attnb@0 (wqkvT aliases until attn), Qb@8M (wprojT
    // aliases after attn), Kb@16M, Vt@24M. xbf lives in d_out until proj.
    char* ws = (char*)d_ws;
    u16* attnb  = (u16*)(ws + 0);
    u16* wqkvT  = (u16*)(ws + 0);
    u16* Qb     = (u16*)(ws + 8388608);
    u16* wprojT = (u16*)(ws + 8388608);
    u16* Kb     = (u16*)(ws + 16777216);
    u16* Vt     = (u16*)(ws + 25165824);
    u16* xbf    = (u16*)d_out;

    prep_k<<<dim3(4288), 256, 0, stream>>>(x, xbf, wq, wqkvT);
    gemm_bt_k<0, 128><<<dim3(64, 12), 256, 0, stream>>>(xbf, wqkvT, bq, Qb, Kb, Vt,
                                                        nullptr);
    attn_k<<<dim3(16, 32), 256, 0, stream>>>(Qb, Kb, Vt, attnb);
    transpose_cvt_k<<<dim3(8, 8), dim3(64, 8), 0, stream>>>(wp, wprojT, 512, 512);
    gemm_bt_k<1, 64><<<dim3(64, 8), 256, 0, stream>>>(attnb, wprojT, bp, nullptr,
                                                      nullptr, nullptr, out);
}